// Round 2
// baseline (33.265 us; speedup 1.0000x reference)
//
#include <hip/hip_runtime.h>

// EquivariantMultiheadAttention — B=4, N=128, S=8, CIN=COUT=8, GDIM=7
//
// Softmax over key dims (j,s2) cancels the query factor exp(y_i*w_y1) and the
// biases exp(b_g+b_y) exactly:
//   out[b,i,s1,c] = ( y[b,i,s1,c] + num/den ) * mask[b,i,s1], then @ w_lin^T
//   num = sum_{j,s2} exp(g.wg[c]) * kw * y[b,j,s2,c]
//   den = sum_{j,s2} exp(g.wg[c]) * kw,   kw = mask[b,j,s2] ? exp(y*w_y[c,0]) : 0
//
// R2: 4-way j-split -> grid 2048, 1 (j,s1) pair per thread, 19 KB LDS,
// launch_bounds(256,4) => 16 waves/CU. Partials to d_ws, tiny finalize kernel.

namespace {

constexpr int kN = 128, kS = 8, kC = 8, kO = 8, kG = 7;
constexpr int kSplit = 4;                 // j-groups of 32
constexpr int kBI = 4 * kN;               // 512 (b,i) slabs
// LDS row stride per j: 64 payload + 4 pad floats. 68%32=4 -> the 8
// concurrently-read j-rows start on banks {0,4,...,28}: each ds_read_b128
// covers 4 banks, 8 rows cover all 32 -> conflict-free with broadcast.
constexpr int JSTRIDE = 68;

__global__ __launch_bounds__(256, 4)
void emha_partial(const float* __restrict__ pg,     // (B,N,N,S,S,G)
                  const float* __restrict__ y,      // (B,N,S,C)
                  const int*   __restrict__ mask,   // (B,N,S) 0/1
                  const float* __restrict__ w_y,    // (C,2)
                  const float* __restrict__ w_g,    // (C,G)
                  float*       __restrict__ ws)     // (split,bi,s1,16) partials
{
    __shared__ float lds_kw[32 * JSTRIDE];   // kw[j_local][s2*8+c]
    __shared__ float lds_kv[32 * JSTRIDE];   // kw*y
    __shared__ float red[4][8][16];          // wave, s1, {num[8],den[8]}

    const int t     = threadIdx.x;
    const int blk   = blockIdx.x;            // bi*4 + split
    const int split = blk & 3;
    const int bi    = blk >> 2;              // b*N + i
    const int b     = bi >> 7;

    // ---- Issue this thread's entire pairwise_g burst first (14 x b128) ----
    // pair index within slab: j*8+s1 = 256*split + t
    const float4* src = reinterpret_cast<const float4*>(
        pg + ((size_t)bi * 1024 + 256 * split + t) * 56);
    float4 pv[14];
#pragma unroll
    for (int q = 0; q < 14; ++q) pv[q] = src[q];

    // uniform weights (uniform addresses -> scalar loads)
    float wg[kC][kG];
#pragma unroll
    for (int c = 0; c < kC; ++c)
#pragma unroll
        for (int g = 0; g < kG; ++g)
            wg[c][g] = w_g[c * kG + g];

    // ---- Phase 1: key tables for this block's 32 j rows (2048 items) ----
    const float* yb = y    + b * (kN * kS * kC) + split * 2048;
    const int*   mb = mask + b * (kN * kS)      + split * 256;
    const float  wy0 = w_y[2 * (t & 7)];     // c == idx&7 == t&7 for all k
#pragma unroll
    for (int k = 0; k < 8; ++k) {
        const int idx = t + k * 256;         // j_local*64 + s2*8 + c
        const float yv = yb[idx];            // coalesced
        const int   m  = mb[idx >> 3];
        const float kw = m ? __expf(yv * wy0) : 0.0f;
        const int off = (idx >> 6) * JSTRIDE + (idx & 63);
        lds_kw[off] = kw;
        lds_kv[off] = kw * yv;
    }
    __syncthreads();   // also drains the pv loads (vmcnt 0 before barrier)

    // ---- Phase 2: one (j,s1) pair per thread ----
    const int jl = t >> 3;                   // local j row
    const float* p = reinterpret_cast<const float*>(pv);
    float num[kC], den[kC];
#pragma unroll
    for (int c = 0; c < kC; ++c) { num[c] = 0.0f; den[c] = 0.0f; }

#pragma unroll
    for (int s2 = 0; s2 < kS; ++s2) {
        const int lo = jl * JSTRIDE + s2 * 8;
        const float4 kva = *reinterpret_cast<const float4*>(&lds_kv[lo]);
        const float4 kvb = *reinterpret_cast<const float4*>(&lds_kv[lo + 4]);
        const float4 kwa = *reinterpret_cast<const float4*>(&lds_kw[lo]);
        const float4 kwb = *reinterpret_cast<const float4*>(&lds_kw[lo + 4]);
        const float kv[8] = {kva.x, kva.y, kva.z, kva.w, kvb.x, kvb.y, kvb.z, kvb.w};
        const float kw[8] = {kwa.x, kwa.y, kwa.z, kwa.w, kwb.x, kwb.y, kwb.z, kwb.w};
#pragma unroll
        for (int c = 0; c < kC; ++c) {
            float d =      p[s2 * kG + 0] * wg[c][0];
            d = fmaf(p[s2 * kG + 1], wg[c][1], d);
            d = fmaf(p[s2 * kG + 2], wg[c][2], d);
            d = fmaf(p[s2 * kG + 3], wg[c][3], d);
            d = fmaf(p[s2 * kG + 4], wg[c][4], d);
            d = fmaf(p[s2 * kG + 5], wg[c][5], d);
            d = fmaf(p[s2 * kG + 6], wg[c][6], d);
            const float e = __expf(d);
            num[c] = fmaf(e, kv[c], num[c]);
            den[c] = fmaf(e, kw[c], den[c]);
        }
    }

    // ---- Phase 3: reduce over j within wave (lanes sharing s1 = t&7) ----
#pragma unroll
    for (int c = 0; c < kC; ++c) {
        num[c] += __shfl_xor(num[c], 8);
        num[c] += __shfl_xor(num[c], 16);
        num[c] += __shfl_xor(num[c], 32);
        den[c] += __shfl_xor(den[c], 8);
        den[c] += __shfl_xor(den[c], 16);
        den[c] += __shfl_xor(den[c], 32);
    }
    const int wave = t >> 6;
    const int lane = t & 63;
    if (lane < 8) {
#pragma unroll
        for (int c = 0; c < kC; ++c) {
            red[wave][lane][c]     = num[c];
            red[wave][lane][c + 8] = den[c];
        }
    }
    __syncthreads();

    // ---- Phase 4: cross-wave sum, write 128 partial floats ----
    if (t < 128) {               // t = s1*16 + idx16
        float v = 0.0f;
#pragma unroll
        for (int w = 0; w < 4; ++w) v += red[w][t >> 4][t & 15];
        ws[(size_t)(split * kBI + bi) * 128 + t] = v;
    }
}

__global__ __launch_bounds__(256)
void emha_finalize(const float* __restrict__ ws,     // (split,bi,s1,16)
                   const float* __restrict__ y,      // (B,N,S,C)
                   const int*   __restrict__ mask,   // (B,N,S)
                   const float* __restrict__ w_lin,  // (O,C)
                   float*       __restrict__ out)    // (B,N,S,O)
{
    const int tid = blockIdx.x * 256 + threadIdx.x;  // 4096 threads
    const int bi  = tid >> 3;
    const int s1  = tid & 7;

    float4 n0 = {0,0,0,0}, n1 = {0,0,0,0}, d0 = {0,0,0,0}, d1 = {0,0,0,0};
#pragma unroll
    for (int s = 0; s < kSplit; ++s) {
        const float4* pp = reinterpret_cast<const float4*>(
            ws + (size_t)(s * kBI + bi) * 128 + s1 * 16);
        const float4 a = pp[0], bq = pp[1], cq = pp[2], dq = pp[3];
        n0.x += a.x;  n0.y += a.y;  n0.z += a.z;  n0.w += a.w;
        n1.x += bq.x; n1.y += bq.y; n1.z += bq.z; n1.w += bq.w;
        d0.x += cq.x; d0.y += cq.y; d0.z += cq.z; d0.w += cq.w;
        d1.x += dq.x; d1.y += dq.y; d1.z += dq.z; d1.w += dq.w;
    }
    const float nn[8] = {n0.x, n0.y, n0.z, n0.w, n1.x, n1.y, n1.z, n1.w};
    const float dd[8] = {d0.x, d0.y, d0.z, d0.w, d1.x, d1.y, d1.z, d1.w};

    const float* yrow = y + (size_t)bi * 64 + s1 * 8;
    const int m = mask[bi * 8 + s1];
    float ob[8];
#pragma unroll
    for (int c = 0; c < kC; ++c)
        ob[c] = m ? (yrow[c] + nn[c] / dd[c]) : 0.0f;

    float o[8];
#pragma unroll
    for (int oo = 0; oo < kO; ++oo) {
        float acc = 0.0f;
#pragma unroll
        for (int c = 0; c < kC; ++c)
            acc = fmaf(ob[c], w_lin[oo * kC + c], acc);
        o[oo] = acc;
    }
    float4* op = reinterpret_cast<float4*>(out + (size_t)bi * 64 + s1 * 8);
    op[0] = make_float4(o[0], o[1], o[2], o[3]);
    op[1] = make_float4(o[4], o[5], o[6], o[7]);
}

} // namespace

extern "C" void kernel_launch(void* const* d_in, const int* in_sizes, int n_in,
                              void* d_out, int out_size, void* d_ws, size_t ws_size,
                              hipStream_t stream)
{
    const float* pg    = (const float*)d_in[0];  // pairwise_g
    const float* y     = (const float*)d_in[1];  // coset_functions
    const int*   mask  = (const int*)  d_in[2];  // mask (bool -> int32)
    const float* w_y   = (const float*)d_in[3];
    // d_in[4] = b_y, d_in[6] = b_g: cancel in the softmax -> unused
    const float* w_g   = (const float*)d_in[5];
    const float* w_lin = (const float*)d_in[7];
    float* out = (float*)d_out;
    float* wsf = (float*)d_ws;                   // needs 1 MB (ws is ~448 MB)

    emha_partial<<<kBI * kSplit, 256, 0, stream>>>(pg, y, mask, w_y, w_g, wsf);
    emha_finalize<<<16, 256, 0, stream>>>(wsf, y, mask, w_lin, out);
}

// Round 3
// 32.505 us; speedup vs baseline: 1.0234x; 1.0234x over previous
//
#include <hip/hip_runtime.h>

// EquivariantMultiheadAttention — B=4, N=128, S=8, CIN=COUT=8, GDIM=7
//
// Softmax over key dims (j,s2) cancels the query factor exp(y_i*w_y1) and the
// biases exp(b_g+b_y) exactly:
//   out[b,i,s1,c] = ( y[b,i,s1,c] + num/den ) * mask[b,i,s1], then @ w_lin^T
//   num = sum_{j,s2} exp(g.wg[c]) * kw * y[b,j,s2,c]
//   den = sum_{j,s2} exp(g.wg[c]) * kw,   kw = mask[b,j,s2] ? exp(y*w_y[c,0]) : 0
//
// R3 = R1 structure (single kernel, one block per (b,i), fp32 LDS tables,
// launch_bounds(256,2) so the allocator has 256 VGPRs — R2's (256,4) spilled)
// + ONE change: register double-buffered prefetch of the pairwise_g payload.
// Each (j,s1) pair's 56 floats are consumed as two 112-B-aligned halves
// (4 s2 each, 7 x float4); half h+1 is issued before computing half h, so HBM
// stays busy during compute instead of alternating drain/compute phases.

namespace {

constexpr int kN = 128, kS = 8, kC = 8, kO = 8, kG = 7;
// LDS row stride per j: 64 payload + 4 pad floats. 68%32=4 -> the 8
// concurrently-read j-rows start on banks {0,4,...,28}; each ds_read_b128
// covers 4 banks, 8 rows cover all 32 -> conflict-free (same-row lanes
// broadcast).
constexpr int JSTRIDE = 68;

__global__ __launch_bounds__(256, 2)
void emha_kernel(const float* __restrict__ pg,     // (B,N,N,S,S,G)
                 const float* __restrict__ y,      // (B,N,S,C)
                 const int*   __restrict__ mask,   // (B,N,S) 0/1
                 const float* __restrict__ w_y,    // (C,2)
                 const float* __restrict__ w_g,    // (C,G)
                 const float* __restrict__ w_lin,  // (O,C)
                 float*       __restrict__ out)    // (B,N,S,O)
{
    __shared__ float lds_kw[kN * JSTRIDE];   // kw[j][s2*8+c]
    __shared__ float lds_kv[kN * JSTRIDE];   // kw*y
    __shared__ float red[4][8][16];          // wave, s1, {num[8],den[8]}
    __shared__ float obuf[8][8];             // s1, c

    const int t  = threadIdx.x;
    const int bi = blockIdx.x;               // b*N + i
    const int b  = bi >> 7;
    const int i  = bi & 127;

    // Per-thread payload base: pair (j*8+s1) = k*256 + t, 56 floats/pair.
    // Half h (h=0..7): floats [ (h>>1)*14336 + t*56 + (h&1)*28 .. +28 )
    const float* pbase = pg + (size_t)bi * (kN * kS * kS * kG) + (size_t)t * 56;

    // ---- Issue half 0 before the table build so it lands under phase 1 ----
    float4 buf[2][7];
    {
        const float4* s0 = reinterpret_cast<const float4*>(pbase);
#pragma unroll
        for (int q = 0; q < 7; ++q) buf[0][q] = s0[q];
    }

    // uniform weights (uniform addresses -> scalar loads)
    float wg[kC][kG];
#pragma unroll
    for (int c = 0; c < kC; ++c)
#pragma unroll
        for (int g = 0; g < kG; ++g)
            wg[c][g] = w_g[c * kG + g];

    // ---- Phase 1: key tables for batch b (8192 items, 32/thread) ----
    const float* yb = y    + b * (kN * kS * kC);
    const int*   mb = mask + b * (kN * kS);
    const float  wy0 = w_y[2 * (t & 7)];     // c == idx&7 == t&7 for all k
#pragma unroll
    for (int k = 0; k < 32; ++k) {
        const int idx = t + k * 256;         // j*64 + s2*8 + c
        const float yv = yb[idx];            // coalesced
        const int   m  = mb[idx >> 3];
        const float kw = m ? __expf(yv * wy0) : 0.0f;
        const int off = (idx >> 6) * JSTRIDE + (idx & 63);
        lds_kw[off] = kw;
        lds_kv[off] = kw * yv;
    }
    __syncthreads();

    // ---- Phase 2: pipelined sweep, 8 halves (k = h>>1, s2 base (h&1)*4) ----
    const int jl = t >> 3;                   // j within group of 32
    float num[kC], den[kC];
#pragma unroll
    for (int c = 0; c < kC; ++c) { num[c] = 0.0f; den[c] = 0.0f; }

#pragma unroll
    for (int h = 0; h < 8; ++h) {
        // prefetch half h+1 into the other buffer (static index after unroll)
        if (h < 7) {
            const int hn = h + 1;
            const float4* sn = reinterpret_cast<const float4*>(
                pbase + (hn >> 1) * 14336 + (hn & 1) * 28);
#pragma unroll
            for (int q = 0; q < 7; ++q) buf[hn & 1][q] = sn[q];
        }

        const float* p = reinterpret_cast<const float*>(buf[h & 1]);
        const int j = (h >> 1) * 32 + jl;
#pragma unroll
        for (int s2i = 0; s2i < 4; ++s2i) {
            const int s2 = (h & 1) * 4 + s2i;
            const int lo = j * JSTRIDE + s2 * 8;
            const float4 kva = *reinterpret_cast<const float4*>(&lds_kv[lo]);
            const float4 kvb = *reinterpret_cast<const float4*>(&lds_kv[lo + 4]);
            const float4 kwa = *reinterpret_cast<const float4*>(&lds_kw[lo]);
            const float4 kwb = *reinterpret_cast<const float4*>(&lds_kw[lo + 4]);
            const float kv[8] = {kva.x, kva.y, kva.z, kva.w, kvb.x, kvb.y, kvb.z, kvb.w};
            const float kw[8] = {kwa.x, kwa.y, kwa.z, kwa.w, kwb.x, kwb.y, kwb.z, kwb.w};
#pragma unroll
            for (int c = 0; c < kC; ++c) {
                float d =      p[s2i * kG + 0] * wg[c][0];
                d = fmaf(p[s2i * kG + 1], wg[c][1], d);
                d = fmaf(p[s2i * kG + 2], wg[c][2], d);
                d = fmaf(p[s2i * kG + 3], wg[c][3], d);
                d = fmaf(p[s2i * kG + 4], wg[c][4], d);
                d = fmaf(p[s2i * kG + 5], wg[c][5], d);
                d = fmaf(p[s2i * kG + 6], wg[c][6], d);
                const float e = __expf(d);
                num[c] = fmaf(e, kv[c], num[c]);
                den[c] = fmaf(e, kw[c], den[c]);
            }
        }
    }

    // ---- Phase 3: reduce 32 threads per s1 (butterfly over 8,16,32) ----
#pragma unroll
    for (int c = 0; c < kC; ++c) {
        num[c] += __shfl_xor(num[c], 8);
        num[c] += __shfl_xor(num[c], 16);
        num[c] += __shfl_xor(num[c], 32);
        den[c] += __shfl_xor(den[c], 8);
        den[c] += __shfl_xor(den[c], 16);
        den[c] += __shfl_xor(den[c], 32);
    }
    const int wave = t >> 6;
    const int lane = t & 63;
    if (lane < 8) {
#pragma unroll
        for (int c = 0; c < kC; ++c) {
            red[wave][lane][c]     = num[c];
            red[wave][lane][c + 8] = den[c];
        }
    }
    __syncthreads();

    // ---- Phase 4: cross-wave reduce + residual + query mask ----
    if (t < 64) {
        const int s1q = t >> 3, c = t & 7;
        float ns = 0.0f, ds = 0.0f;
#pragma unroll
        for (int w = 0; w < 4; ++w) { ns += red[w][s1q][c]; ds += red[w][s1q][c + 8]; }
        const float yv = yb[(i * kS + s1q) * kC + c];
        const int   m  = mb[i * kS + s1q];
        obuf[s1q][c] = m ? (yv + ns / ds) : 0.0f;
    }
    __syncthreads();

    // ---- Phase 5: output linear (c -> o), coalesced 64-float store ----
    if (t < 64) {
        const int s1q = t >> 3, o = t & 7;
        float acc = 0.0f;
#pragma unroll
        for (int c = 0; c < kC; ++c)
            acc = fmaf(obuf[s1q][c], w_lin[o * kC + c], acc);
        out[(size_t)bi * (kS * kO) + t] = acc;
    }
}

} // namespace

extern "C" void kernel_launch(void* const* d_in, const int* in_sizes, int n_in,
                              void* d_out, int out_size, void* d_ws, size_t ws_size,
                              hipStream_t stream)
{
    const float* pg    = (const float*)d_in[0];  // pairwise_g
    const float* y     = (const float*)d_in[1];  // coset_functions
    const int*   mask  = (const int*)  d_in[2];  // mask (bool -> int32)
    const float* w_y   = (const float*)d_in[3];
    // d_in[4] = b_y, d_in[6] = b_g: cancel in the softmax -> unused
    const float* w_g   = (const float*)d_in[5];
    const float* w_lin = (const float*)d_in[7];
    float* out = (float*)d_out;

    emha_kernel<<<4 * kN, 256, 0, stream>>>(pg, y, mask, w_y, w_g, w_lin, out);
}

// Round 4
// 29.217 us; speedup vs baseline: 1.1385x; 1.1125x over previous
//
#include <hip/hip_runtime.h>

// EquivariantMultiheadAttention — B=4, N=128, S=8, CIN=COUT=8, GDIM=7
//
// Softmax over key dims (j,s2) cancels the query factor exp(y_i*w_y1) and the
// biases exp(b_g+b_y) exactly:
//   out[b,i,s1,c] = ( y[b,i,s1,c] + num/den ) * mask[b,i,s1], then @ w_lin^T
//   num = sum_{j,s2} exp(g.wg[c]) * kw * y[b,j,s2,c]
//   den = sum_{j,s2} exp(g.wg[c]) * kw,   kw = mask[b,j,s2] ? exp(y*w_y[c,0]) : 0
//
// R4 = R1 with 512-thread blocks (8 waves) instead of 256: one block per
// (b,i), 2 (j,s1) pairs per thread -> 16 waves/CU = 4 waves/SIMD (R1 had 2).
// Memory and compute phases of different waves now interleave instead of
// running in lockstep. Payload consumed in 28-float chunks (single 7xfloat4
// buffer, outer pair loop unroll 1) to fit the 128-VGPR cap of (512,4)
// without spilling (R2's failure mode). fp32 tables -> math identical to R1.

namespace {

constexpr int kN = 128, kS = 8, kC = 8, kO = 8, kG = 7;
// LDS row stride per j: 64 payload + 4 pad floats. 68%32=4 -> the 8
// concurrently-read j-rows start on banks {0,4,...,28}; each ds_read_b128
// covers 4 banks, 8 rows cover all 32 -> conflict-free (same-row lanes
// broadcast).
constexpr int JSTRIDE = 68;

__global__ __launch_bounds__(512, 4)
void emha_kernel(const float* __restrict__ pg,     // (B,N,N,S,S,G)
                 const float* __restrict__ y,      // (B,N,S,C)
                 const int*   __restrict__ mask,   // (B,N,S) 0/1
                 const float* __restrict__ w_y,    // (C,2)
                 const float* __restrict__ w_g,    // (C,G)
                 const float* __restrict__ w_lin,  // (O,C)
                 float*       __restrict__ out)    // (B,N,S,O)
{
    __shared__ float lds_kw[kN * JSTRIDE];   // kw[j][s2*8+c]
    __shared__ float lds_kv[kN * JSTRIDE];   // kw*y
    __shared__ float red[8][8][16];          // wave, s1, {num[8],den[8]}
    __shared__ float obuf[8][8];             // s1, c

    const int t  = threadIdx.x;              // 0..511
    const int bi = blockIdx.x;               // b*N + i
    const int b  = bi >> 7;
    const int i  = bi & 127;

    // uniform weights: constant indices off a uniform pointer -> s_load;
    // fmaf(v, s, v) keeps them as the single allowed SGPR operand.
    float wg[kC][kG];
#pragma unroll
    for (int c = 0; c < kC; ++c)
#pragma unroll
        for (int g = 0; g < kG; ++g)
            wg[c][g] = w_g[c * kG + g];

    // ---- Phase 1: key tables for batch b (8192 items, 16/thread) ----
    const float* yb = y    + b * (kN * kS * kC);
    const int*   mb = mask + b * (kN * kS);
    const float  wy0 = w_y[2 * (t & 7)];     // c == idx&7 == t&7 for all k
#pragma unroll
    for (int k = 0; k < 16; ++k) {
        const int idx = t + k * 512;         // j*64 + s2*8 + c
        const float yv = yb[idx];            // coalesced
        const int   m  = mb[idx >> 3];
        const float kw = m ? __expf(yv * wy0) : 0.0f;
        const int off = (idx >> 6) * JSTRIDE + (idx & 63);
        lds_kw[off] = kw;
        lds_kv[off] = kw * yv;
    }
    __syncthreads();

    // ---- Phase 2: 2 pairs/thread, each pair as 2 halves of 4 s2 ----
    const int jbase = t >> 3;                // 0..63
    const float* pb = pg + (size_t)bi * (kN * kS * kS * kG) + (size_t)t * 56;
    float num[kC], den[kC];
#pragma unroll
    for (int c = 0; c < kC; ++c) { num[c] = 0.0f; den[c] = 0.0f; }

#pragma unroll 1
    for (int k = 0; k < 2; ++k) {            // pair index = k*512 + t
        const int j = k * 64 + jbase;
        const float* ppair = pb + k * 28672; // 512 pairs * 56 floats
#pragma unroll
        for (int h = 0; h < 2; ++h) {        // half: s2 in [h*4, h*4+4)
            float4 buf[7];                   // 28 floats = 4 s2 * 7 g
            const float4* src = reinterpret_cast<const float4*>(ppair + h * 28);
#pragma unroll
            for (int q = 0; q < 7; ++q) buf[q] = src[q];
            const float* p = reinterpret_cast<const float*>(buf);

#pragma unroll
            for (int s2i = 0; s2i < 4; ++s2i) {
                const int lo = j * JSTRIDE + (h * 4 + s2i) * 8;
                const float4 kva = *reinterpret_cast<const float4*>(&lds_kv[lo]);
                const float4 kvb = *reinterpret_cast<const float4*>(&lds_kv[lo + 4]);
                const float4 kwa = *reinterpret_cast<const float4*>(&lds_kw[lo]);
                const float4 kwb = *reinterpret_cast<const float4*>(&lds_kw[lo + 4]);
                const float kv[8] = {kva.x, kva.y, kva.z, kva.w, kvb.x, kvb.y, kvb.z, kvb.w};
                const float kw[8] = {kwa.x, kwa.y, kwa.z, kwa.w, kwb.x, kwb.y, kwb.z, kwb.w};
#pragma unroll
                for (int c = 0; c < kC; ++c) {
                    float d =      p[s2i * kG + 0] * wg[c][0];
                    d = fmaf(p[s2i * kG + 1], wg[c][1], d);
                    d = fmaf(p[s2i * kG + 2], wg[c][2], d);
                    d = fmaf(p[s2i * kG + 3], wg[c][3], d);
                    d = fmaf(p[s2i * kG + 4], wg[c][4], d);
                    d = fmaf(p[s2i * kG + 5], wg[c][5], d);
                    d = fmaf(p[s2i * kG + 6], wg[c][6], d);
                    const float e = __expf(d);
                    num[c] = fmaf(e, kv[c], num[c]);
                    den[c] = fmaf(e, kw[c], den[c]);
                }
            }
        }
    }

    // ---- Phase 3: reduce lanes sharing s1 (butterfly over 8,16,32) ----
#pragma unroll
    for (int c = 0; c < kC; ++c) {
        num[c] += __shfl_xor(num[c], 8);
        num[c] += __shfl_xor(num[c], 16);
        num[c] += __shfl_xor(num[c], 32);
        den[c] += __shfl_xor(den[c], 8);
        den[c] += __shfl_xor(den[c], 16);
        den[c] += __shfl_xor(den[c], 32);
    }
    const int wave = t >> 6;                 // 0..7
    const int lane = t & 63;
    if (lane < 8) {
#pragma unroll
        for (int c = 0; c < kC; ++c) {
            red[wave][lane][c]     = num[c];
            red[wave][lane][c + 8] = den[c];
        }
    }
    __syncthreads();

    // ---- Phase 4: cross-wave reduce + residual + query mask ----
    if (t < 64) {
        const int s1q = t >> 3, c = t & 7;
        float ns = 0.0f, ds = 0.0f;
#pragma unroll
        for (int w = 0; w < 8; ++w) { ns += red[w][s1q][c]; ds += red[w][s1q][c + 8]; }
        const float yv = yb[(i * kS + s1q) * kC + c];
        const int   m  = mb[i * kS + s1q];
        obuf[s1q][c] = m ? (yv + ns / ds) : 0.0f;
    }
    __syncthreads();

    // ---- Phase 5: output linear (c -> o), coalesced 64-float store ----
    if (t < 64) {
        const int s1q = t >> 3, o = t & 7;
        float acc = 0.0f;
#pragma unroll
        for (int c = 0; c < kC; ++c)
            acc = fmaf(obuf[s1q][c], w_lin[o * kC + c], acc);
        out[(size_t)bi * (kS * kO) + t] = acc;
    }
}

} // namespace

extern "C" void kernel_launch(void* const* d_in, const int* in_sizes, int n_in,
                              void* d_out, int out_size, void* d_ws, size_t ws_size,
                              hipStream_t stream)
{
    const float* pg    = (const float*)d_in[0];  // pairwise_g
    const float* y     = (const float*)d_in[1];  // coset_functions
    const int*   mask  = (const int*)  d_in[2];  // mask (bool -> int32)
    const float* w_y   = (const float*)d_in[3];
    // d_in[4] = b_y, d_in[6] = b_g: cancel in the softmax -> unused
    const float* w_g   = (const float*)d_in[5];
    const float* w_lin = (const float*)d_in[7];
    float* out = (float*)d_out;

    emha_kernel<<<4 * kN, 512, 0, stream>>>(pg, y, mask, w_y, w_g, w_lin, out);
}